// Round 9
// baseline (1639.773 us; speedup 1.0000x reference)
//
#include <hip/hip_runtime.h>

#define N_NODES 100000
#define N_EDGES 1600000
#define D 64
#define NBUCKET 391              // ceil(N_NODES/256), bucket = 256 dst nodes
#define QCAP_B 4800              // per-bucket queue cap (mean 4096, sd 64)
#define EPB 4096                 // edges per sort block
#define SORT_BLOCKS 391          // ceil(N_EDGES/EPB)

typedef unsigned short u16;

__device__ __forceinline__ float bf2f(u16 u) {
    unsigned v = (unsigned)u << 16;
    float f;
    __builtin_memcpy(&f, &v, 4);
    return f;
}
__device__ __forceinline__ u16 f2bf(float f) {
    unsigned u;
    __builtin_memcpy(&u, &f, 4);
    u = (u + 0x7FFFu + ((u >> 16) & 1u)) >> 16;
    return (u16)u;
}

// ---------------------------------------------------------------------------
// x (f32) -> xb (bf16), 4 elems/thread.
// ---------------------------------------------------------------------------
__global__ __launch_bounds__(256) void convert_kernel(
    const float* __restrict__ x, u16* __restrict__ xb)
{
    int i = blockIdx.x * 256 + threadIdx.x;
    float4 v = ((const float4*)x)[i];
    ushort4 o;
    o.x = f2bf(v.x); o.y = f2bf(v.y); o.z = f2bf(v.z); o.w = f2bf(v.w);
    ((ushort4*)xb)[i] = o;
}

// ---------------------------------------------------------------------------
// Block-level counting sort of 4096 edges into 391 bucket queues.
// Pass A: LDS histogram. Scan (Hillis-Steele over 512 with 256 threads).
// One global atomic PER BUCKET PER BLOCK reserves queue space. Pass B:
// re-read edges (L2-warm), place entry into LDS ordered by bucket, record
// its global position. Copy-out is bucket-ordered -> runs of ~10 sequential
// queue slots (vs per-edge random scatter = the r8 63MB writeback bug).
// Entry packs (dst&255)<<17 | src  (src < 2^17).
// ---------------------------------------------------------------------------
__global__ __launch_bounds__(256) void sort_kernel(
    const int* __restrict__ ei, int* __restrict__ qtail,
    unsigned* __restrict__ queue)
{
    __shared__ int cnt[512];      // per-bucket count
    __shared__ int scan[512];     // inclusive scan of cnt
    __shared__ int gbase[512];    // global base in bucket queue
    __shared__ int run[512];      // running rank in pass B
    __shared__ unsigned staged[EPB];
    __shared__ int gposa[EPB];

    int tid = threadIdx.x;
    int e0 = blockIdx.x * EPB;

    cnt[tid] = 0; cnt[tid + 256] = 0;
    run[tid] = 0; run[tid + 256] = 0;
    __syncthreads();

    // pass A: histogram
    for (int i = tid; i < EPB; i += 256) {
        int e = e0 + i;
        if (e < N_EDGES) {
            int dst = ei[N_EDGES + e];
            atomicAdd(&cnt[dst >> 8], 1);
        }
    }
    __syncthreads();
    scan[tid] = cnt[tid]; scan[tid + 256] = cnt[tid + 256];
    __syncthreads();
    // inclusive scan over 512 entries, 256 threads handle 2 each
    for (int off = 1; off < 512; off <<= 1) {
        int v1 = (tid >= off) ? scan[tid - off] : 0;
        int v2 = scan[tid + 256 - off];
        __syncthreads();
        scan[tid] += v1;
        scan[tid + 256] += v2;
        __syncthreads();
    }
    // reserve global queue space: one atomic per non-empty bucket
    if (tid < NBUCKET && cnt[tid] > 0)
        gbase[tid] = atomicAdd(&qtail[tid], cnt[tid]);
    int b2 = tid + 256;
    if (b2 < NBUCKET && cnt[b2] > 0)
        gbase[b2] = atomicAdd(&qtail[b2], cnt[b2]);
    __syncthreads();

    // pass B: place entries (bucket-ordered in LDS) + compute global pos
    for (int i = tid; i < EPB; i += 256) {
        int e = e0 + i;
        if (e < N_EDGES) {
            int dst = ei[N_EDGES + e];
            int src = ei[e];
            int b = dst >> 8;
            int r = atomicAdd(&run[b], 1);
            int slot = scan[b] - cnt[b] + r;           // exclusive base + rank
            staged[slot] = ((unsigned)(dst & 255) << 17) | (unsigned)src;
            int gp = gbase[b] + r;
            gposa[slot] = (gp < QCAP_B) ? b * QCAP_B + gp : -1;
        }
    }
    __syncthreads();

    // copy-out: bucket-ordered -> mostly-sequential queue writes
    int total = scan[511];
    for (int i = tid; i < total; i += 256) {
        int gp = gposa[i];
        if (gp >= 0) queue[gp] = staged[i];
    }
}

// ---------------------------------------------------------------------------
// Fused gather-aggregate: one block per bucket of 256 nodes. The bucket's
// full 256x64 fp32 accumulator lives in 64KB LDS. Stream the bucket's dense
// queue; per entry the wave gathers one bf16 row (128B, LLC-served) and
// ds_add_f32's it into the dst row (banks: lane%32, 2-way alias = free).
// No global atomics, no scattered global writes; epilogue adds self-row and
// writes xa dense bf16.
// ---------------------------------------------------------------------------
__global__ __launch_bounds__(256) void aggregate_kernel(
    const u16* __restrict__ xb, const int* __restrict__ qtail,
    const unsigned* __restrict__ queue, u16* __restrict__ xa)
{
    __shared__ float acc[256 * D];   // 65536 B

    int tid  = threadIdx.x;
    int lane = tid & 63;
    int w    = tid >> 6;
    int b    = blockIdx.x;

    for (int i = tid; i < 256 * D; i += 256) acc[i] = 0.f;
    __syncthreads();

    int n = min(qtail[b], QCAP_B);
    const unsigned* q = queue + (size_t)b * QCAP_B;

    for (int c = w * 64; c < n; c += 256) {
        int m = min(64, n - c);
        unsigned evec = (lane < m) ? q[c + lane] : 0;
        int j = 0;
        for (; j + 8 <= m; j += 8) {
            unsigned e0 = __shfl(evec, j);
            unsigned e1 = __shfl(evec, j + 1);
            unsigned e2 = __shfl(evec, j + 2);
            unsigned e3 = __shfl(evec, j + 3);
            unsigned e4 = __shfl(evec, j + 4);
            unsigned e5 = __shfl(evec, j + 5);
            unsigned e6 = __shfl(evec, j + 6);
            unsigned e7 = __shfl(evec, j + 7);
            u16 v0 = xb[(size_t)(e0 & 0x1FFFFu) * D + lane];
            u16 v1 = xb[(size_t)(e1 & 0x1FFFFu) * D + lane];
            u16 v2 = xb[(size_t)(e2 & 0x1FFFFu) * D + lane];
            u16 v3 = xb[(size_t)(e3 & 0x1FFFFu) * D + lane];
            u16 v4 = xb[(size_t)(e4 & 0x1FFFFu) * D + lane];
            u16 v5 = xb[(size_t)(e5 & 0x1FFFFu) * D + lane];
            u16 v6 = xb[(size_t)(e6 & 0x1FFFFu) * D + lane];
            u16 v7 = xb[(size_t)(e7 & 0x1FFFFu) * D + lane];
            atomicAdd(&acc[(e0 >> 17) * D + lane], bf2f(v0));
            atomicAdd(&acc[(e1 >> 17) * D + lane], bf2f(v1));
            atomicAdd(&acc[(e2 >> 17) * D + lane], bf2f(v2));
            atomicAdd(&acc[(e3 >> 17) * D + lane], bf2f(v3));
            atomicAdd(&acc[(e4 >> 17) * D + lane], bf2f(v4));
            atomicAdd(&acc[(e5 >> 17) * D + lane], bf2f(v5));
            atomicAdd(&acc[(e6 >> 17) * D + lane], bf2f(v6));
            atomicAdd(&acc[(e7 >> 17) * D + lane], bf2f(v7));
        }
        for (; j < m; ++j) {
            unsigned e = __shfl(evec, j);
            u16 v = xb[(size_t)(e & 0x1FFFFu) * D + lane];
            atomicAdd(&acc[(e >> 17) * D + lane], bf2f(v));
        }
    }
    __syncthreads();

    // epilogue: add self row, write dense bf16
    for (int r = w; r < 256; r += 4) {
        int node = b * 256 + r;
        if (node < N_NODES) {
            float v = acc[r * D + lane] + bf2f(xb[(size_t)node * D + lane]);
            xa[(size_t)node * D + lane] = f2bf(v);
        }
    }
}

// ---------------------------------------------------------------------------
// Fused GIN MLP, wave-cooperative, 2 nodes per lane (128 nodes/block).
// (unchanged from round 8)
// ---------------------------------------------------------------------------
#define LP 65

template <int WRITE_BF16>
__global__ __launch_bounds__(256) void gin_mlp_kernel(
    const u16* __restrict__ xa,
    const float* __restrict__ W1, const float* __restrict__ b1,
    const float* __restrict__ W2, const float* __restrict__ b2,
    float* __restrict__ outf, u16* __restrict__ outb)
{
    __shared__ float xs[128 * LP];

    int tid  = threadIdx.x;
    int lane = tid & 63;
    int wq   = __builtin_amdgcn_readfirstlane(tid >> 6);
    int n0   = blockIdx.x * 128;

    for (int f = tid; f < 128 * 16; f += 256) {
        int row = f >> 4, c = f & 15;
        ushort4 v = make_ushort4(0, 0, 0, 0);
        if (n0 + row < N_NODES)
            v = ((const ushort4*)xa)[(size_t)(n0 + row) * 16 + c];
        float* d = &xs[row * LP + c * 4];
        d[0] = bf2f(v.x); d[1] = bf2f(v.y); d[2] = bf2f(v.z); d[3] = bf2f(v.w);
    }
    __syncthreads();

    float acc0[16], acc1[16];
#pragma unroll
    for (int j = 0; j < 16; ++j) { acc0[j] = b1[wq * 16 + j]; acc1[j] = acc0[j]; }
#pragma unroll 2
    for (int k = 0; k < D; ++k) {
        float t0 = xs[lane * LP + k];
        float t1 = xs[(lane + 64) * LP + k];
        const float4* wp = (const float4*)(W1 + k * D + wq * 16);
#pragma unroll
        for (int q = 0; q < 4; ++q) {
            float4 w = wp[q];
#pragma unroll
            for (int j = 0; j < 4; ++j) {
                float wv = ((const float*)&w)[j];
                acc0[q * 4 + j] = fmaf(t0, wv, acc0[q * 4 + j]);
                acc1[q * 4 + j] = fmaf(t1, wv, acc1[q * 4 + j]);
            }
        }
    }
    __syncthreads();
#pragma unroll
    for (int j = 0; j < 16; ++j) {
        xs[lane * LP + wq * 16 + j]        = fmaxf(acc0[j], 0.f);
        xs[(lane + 64) * LP + wq * 16 + j] = fmaxf(acc1[j], 0.f);
    }
    __syncthreads();

#pragma unroll
    for (int j = 0; j < 16; ++j) { acc0[j] = b2[wq * 16 + j]; acc1[j] = acc0[j]; }
#pragma unroll 2
    for (int k = 0; k < D; ++k) {
        float t0 = xs[lane * LP + k];
        float t1 = xs[(lane + 64) * LP + k];
        const float4* wp = (const float4*)(W2 + k * D + wq * 16);
#pragma unroll
        for (int q = 0; q < 4; ++q) {
            float4 w = wp[q];
#pragma unroll
            for (int j = 0; j < 4; ++j) {
                float wv = ((const float*)&w)[j];
                acc0[q * 4 + j] = fmaf(t0, wv, acc0[q * 4 + j]);
                acc1[q * 4 + j] = fmaf(t1, wv, acc1[q * 4 + j]);
            }
        }
    }

#pragma unroll
    for (int i = 0; i < 2; ++i) {
        int node = n0 + lane + 64 * i;
        if (node >= N_NODES) continue;
        float* a = i ? acc1 : acc0;
        if (WRITE_BF16) {
            u16* hp = outb + (size_t)node * D + wq * 16;
#pragma unroll
            for (int j = 0; j < 16; j += 2) {
                ushort2 pv;
                pv.x = f2bf(fmaxf(a[j], 0.f));
                pv.y = f2bf(fmaxf(a[j + 1], 0.f));
                *((ushort2*)(hp + j)) = pv;
            }
        } else {
            float* op = outf + (size_t)node * D + wq * 16;
#pragma unroll
            for (int q = 0; q < 4; ++q) {
                float4 w;
                w.x = a[q * 4]; w.y = a[q * 4 + 1];
                w.z = a[q * 4 + 2]; w.w = a[q * 4 + 3];
                ((float4*)op)[q] = w;
            }
        }
    }
}

extern "C" void kernel_launch(void* const* d_in, const int* in_sizes, int n_in,
                              void* d_out, int out_size, void* d_ws, size_t ws_size,
                              hipStream_t stream)
{
    const float* x  = (const float*)d_in[0];
    const int*   ei = (const int*)d_in[1];
    const float* W1 = (const float*)d_in[2];
    const float* b1 = (const float*)d_in[3];
    const float* W2 = (const float*)d_in[4];
    const float* b2 = (const float*)d_in[5];
    float* out = (float*)d_out;

    // workspace (~33.2 MB):
    //   qtail (512 ints) | queue (391*4800 u32 = 7.5MB)
    //   xa_b (12.8MB bf16) | xb_b (12.8MB bf16; becomes hb after mlp1)
    int* qtail      = (int*)d_ws;
    unsigned* queue = (unsigned*)(qtail + 512);
    u16* xa_b       = (u16*)(queue + (size_t)NBUCKET * QCAP_B);
    u16* xb_b       = xa_b + (size_t)N_NODES * D;

    const int mlp_blocks = (N_NODES + 127) / 128;   // 782

    // ---- prep: qtail zero, x -> bf16, bucket sort ----
    hipMemsetAsync(qtail, 0, 512 * sizeof(int), stream);
    convert_kernel<<<(N_NODES * D / 4) / 256, 256, 0, stream>>>(x, xb_b);
    sort_kernel<<<SORT_BLOCKS, 256, 0, stream>>>(ei, qtail, queue);

    // ---- layer 1: hb = relu(MLP(xb + gather(xb))) ----
    aggregate_kernel<<<NBUCKET, 256, 0, stream>>>(xb_b, qtail, queue, xa_b);
    gin_mlp_kernel<1><<<mlp_blocks, 256, 0, stream>>>(xa_b, W1, b1, W2, b2, nullptr, xb_b);

    // ---- layer 2: out = MLP(hb + gather(hb)) ----
    aggregate_kernel<<<NBUCKET, 256, 0, stream>>>(xb_b, qtail, queue, xa_b);
    gin_mlp_kernel<0><<<mlp_blocks, 256, 0, stream>>>(xa_b, W1, b1, W2, b2, out, nullptr);
}

// Round 10
// 283.390 us; speedup vs baseline: 5.7863x; 5.7863x over previous
//
#include <hip/hip_runtime.h>

#define N_NODES 100000
#define N_EDGES 1600000
#define D 64
#define NBUCKET 391              // ceil(N_NODES/256), bucket = 256 dst nodes
#define QCAP_B 4800              // per-bucket queue cap (mean 4096, sd ~64)
#define EPB 4096                 // edges per sort block
#define SORT_BLOCKS 391          // ceil(N_EDGES/EPB)

typedef unsigned short u16;

__device__ __forceinline__ float bf2f(u16 u) {
    unsigned v = (unsigned)u << 16;
    float f;
    __builtin_memcpy(&f, &v, 4);
    return f;
}
__device__ __forceinline__ u16 f2bf(float f) {
    unsigned u;
    __builtin_memcpy(&u, &f, 4);
    u = (u + 0x7FFFu + ((u >> 16) & 1u)) >> 16;
    return (u16)u;
}

// ---------------------------------------------------------------------------
// x (f32) -> xb (bf16), 4 elems/thread.
// ---------------------------------------------------------------------------
__global__ __launch_bounds__(256) void convert_kernel(
    const float* __restrict__ x, u16* __restrict__ xb)
{
    int i = blockIdx.x * 256 + threadIdx.x;
    float4 v = ((const float4*)x)[i];
    ushort4 o;
    o.x = f2bf(v.x); o.y = f2bf(v.y); o.z = f2bf(v.z); o.w = f2bf(v.w);
    ((ushort4*)xb)[i] = o;
}

// ---------------------------------------------------------------------------
// Block-level counting sort of 4096 edges into 391 bucket queues (verified
// in r9). One global atomic PER BUCKET PER BLOCK (~150k total — cheap);
// copy-out is bucket-ordered -> mostly-sequential queue writes.
// Entry packs (dst&255)<<17 | src  (src < 2^17).
// ---------------------------------------------------------------------------
__global__ __launch_bounds__(256) void sort_kernel(
    const int* __restrict__ ei, int* __restrict__ qtail,
    unsigned* __restrict__ queue)
{
    __shared__ int cnt[512];
    __shared__ int scan[512];
    __shared__ int gbase[512];
    __shared__ int run[512];
    __shared__ unsigned staged[EPB];
    __shared__ int gposa[EPB];

    int tid = threadIdx.x;
    int e0 = blockIdx.x * EPB;

    cnt[tid] = 0; cnt[tid + 256] = 0;
    run[tid] = 0; run[tid + 256] = 0;
    __syncthreads();

    for (int i = tid; i < EPB; i += 256) {
        int e = e0 + i;
        if (e < N_EDGES) {
            int dst = ei[N_EDGES + e];
            atomicAdd(&cnt[dst >> 8], 1);
        }
    }
    __syncthreads();
    scan[tid] = cnt[tid]; scan[tid + 256] = cnt[tid + 256];
    __syncthreads();
    for (int off = 1; off < 512; off <<= 1) {
        int v1 = (tid >= off) ? scan[tid - off] : 0;
        int v2 = scan[tid + 256 - off];
        __syncthreads();
        scan[tid] += v1;
        scan[tid + 256] += v2;
        __syncthreads();
    }
    if (tid < NBUCKET && cnt[tid] > 0)
        gbase[tid] = atomicAdd(&qtail[tid], cnt[tid]);
    int b2 = tid + 256;
    if (b2 < NBUCKET && cnt[b2] > 0)
        gbase[b2] = atomicAdd(&qtail[b2], cnt[b2]);
    __syncthreads();

    for (int i = tid; i < EPB; i += 256) {
        int e = e0 + i;
        if (e < N_EDGES) {
            int dst = ei[N_EDGES + e];
            int src = ei[e];
            int b = dst >> 8;
            int r = atomicAdd(&run[b], 1);
            int slot = scan[b] - cnt[b] + r;
            staged[slot] = ((unsigned)(dst & 255) << 17) | (unsigned)src;
            int gp = gbase[b] + r;
            gposa[slot] = (gp < QCAP_B) ? b * QCAP_B + gp : -1;
        }
    }
    __syncthreads();

    int total = scan[511];
    for (int i = tid; i < total; i += 256) {
        int gp = gposa[i];
        if (gp >= 0) queue[gp] = staged[i];
    }
}

// ---------------------------------------------------------------------------
// Per-bucket LDS counting sort -> exact CSR. One block per bucket: read the
// dense ~16KB queue, histogram 256 rel-dst counters in LDS, scan, write
// row_start/cnt (dense coalesced) and node-grouped src ids into the
// block-private 19KB slab region. ZERO global atomics (r5-r8 showed each
// global atomic costs a memory-side RMW ~40B -> the invariant 63MB).
// ---------------------------------------------------------------------------
__global__ __launch_bounds__(256) void bin3_kernel(
    const unsigned* __restrict__ queue, const int* __restrict__ qtail,
    int* __restrict__ cnt_out, int* __restrict__ row_start,
    int* __restrict__ sorted_src)
{
    __shared__ int cnt[256];
    __shared__ int scanv[256];
    __shared__ int run[256];
    __shared__ unsigned staged[QCAP_B];   // 19.2 KB

    int tid = threadIdx.x;
    int b = blockIdx.x;
    cnt[tid] = 0; run[tid] = 0;
    __syncthreads();

    int n = min(qtail[b], QCAP_B);
    const unsigned* q = queue + (size_t)b * QCAP_B;

    for (int i = tid; i < n; i += 256) {
        unsigned e = q[i];
        staged[i] = e;
        atomicAdd(&cnt[e >> 17], 1);
    }
    __syncthreads();
    scanv[tid] = cnt[tid];
    __syncthreads();
    for (int off = 1; off < 256; off <<= 1) {
        int v = (tid >= off) ? scanv[tid - off] : 0;
        __syncthreads();
        scanv[tid] += v;
        __syncthreads();
    }

    int gb = b * QCAP_B;
    int node = b * 256 + tid;
    if (node < N_NODES) {
        cnt_out[node] = cnt[tid];
        row_start[node] = gb + scanv[tid] - cnt[tid];
    }

    for (int i = tid; i < n; i += 256) {
        unsigned e = staged[i];
        int r = (int)(e >> 17);
        int k = atomicAdd(&run[r], 1);
        int pos = gb + (scanv[r] - cnt[r]) + k;
        sorted_src[pos] = (int)(e & 0x1FFFFu);
    }
}

// ---------------------------------------------------------------------------
// Gather aggregation (r8 structure, CSR-fed): xa[i] = xb[i] + sum xb[src].
// One wave per node (100k waves -> full occupancy), lane = feature,
// bf16 rows (128B LLC-served), shfl-broadcast + ILP-8 gathers.
// ---------------------------------------------------------------------------
__global__ __launch_bounds__(256) void aggregate_kernel(
    const u16* __restrict__ xb, const int* __restrict__ cnt_arr,
    const int* __restrict__ row_start, const int* __restrict__ sorted_src,
    u16* __restrict__ xa)
{
    int node = blockIdx.x * 4 + (threadIdx.x >> 6);
    int lane = threadIdx.x & 63;
    if (node >= N_NODES) return;

    int cnt = cnt_arr[node];
    int base = row_start[node];

    float a0 = bf2f(xb[(size_t)node * D + lane]);
    float a1 = 0.f, a2 = 0.f, a3 = 0.f;
    float a4 = 0.f, a5 = 0.f, a6 = 0.f, a7 = 0.f;

    for (int c = 0; c < cnt; c += 64) {
        int m = min(64, cnt - c);
        int s_vec = (lane < m) ? sorted_src[base + c + lane] : 0;
        int j = 0;
        for (; j + 8 <= m; j += 8) {
            int s0 = __shfl(s_vec, j);
            int s1 = __shfl(s_vec, j + 1);
            int s2 = __shfl(s_vec, j + 2);
            int s3 = __shfl(s_vec, j + 3);
            int s4 = __shfl(s_vec, j + 4);
            int s5 = __shfl(s_vec, j + 5);
            int s6 = __shfl(s_vec, j + 6);
            int s7 = __shfl(s_vec, j + 7);
            u16 v0 = xb[(size_t)s0 * D + lane];
            u16 v1 = xb[(size_t)s1 * D + lane];
            u16 v2 = xb[(size_t)s2 * D + lane];
            u16 v3 = xb[(size_t)s3 * D + lane];
            u16 v4 = xb[(size_t)s4 * D + lane];
            u16 v5 = xb[(size_t)s5 * D + lane];
            u16 v6 = xb[(size_t)s6 * D + lane];
            u16 v7 = xb[(size_t)s7 * D + lane];
            a0 += bf2f(v0); a1 += bf2f(v1); a2 += bf2f(v2); a3 += bf2f(v3);
            a4 += bf2f(v4); a5 += bf2f(v5); a6 += bf2f(v6); a7 += bf2f(v7);
        }
        for (; j + 4 <= m; j += 4) {
            int s0 = __shfl(s_vec, j);
            int s1 = __shfl(s_vec, j + 1);
            int s2 = __shfl(s_vec, j + 2);
            int s3 = __shfl(s_vec, j + 3);
            a0 += bf2f(xb[(size_t)s0 * D + lane]);
            a1 += bf2f(xb[(size_t)s1 * D + lane]);
            a2 += bf2f(xb[(size_t)s2 * D + lane]);
            a3 += bf2f(xb[(size_t)s3 * D + lane]);
        }
        for (; j < m; ++j) {
            int s = __shfl(s_vec, j);
            a0 += bf2f(xb[(size_t)s * D + lane]);
        }
    }
    float tot = ((a0 + a1) + (a2 + a3)) + ((a4 + a5) + (a6 + a7));
    xa[(size_t)node * D + lane] = f2bf(tot);
}

// ---------------------------------------------------------------------------
// Fused GIN MLP, wave-cooperative, 2 nodes per lane (unchanged from r8).
// ---------------------------------------------------------------------------
#define LP 65

template <int WRITE_BF16>
__global__ __launch_bounds__(256) void gin_mlp_kernel(
    const u16* __restrict__ xa,
    const float* __restrict__ W1, const float* __restrict__ b1,
    const float* __restrict__ W2, const float* __restrict__ b2,
    float* __restrict__ outf, u16* __restrict__ outb)
{
    __shared__ float xs[128 * LP];

    int tid  = threadIdx.x;
    int lane = tid & 63;
    int wq   = __builtin_amdgcn_readfirstlane(tid >> 6);
    int n0   = blockIdx.x * 128;

    for (int f = tid; f < 128 * 16; f += 256) {
        int row = f >> 4, c = f & 15;
        ushort4 v = make_ushort4(0, 0, 0, 0);
        if (n0 + row < N_NODES)
            v = ((const ushort4*)xa)[(size_t)(n0 + row) * 16 + c];
        float* d = &xs[row * LP + c * 4];
        d[0] = bf2f(v.x); d[1] = bf2f(v.y); d[2] = bf2f(v.z); d[3] = bf2f(v.w);
    }
    __syncthreads();

    float acc0[16], acc1[16];
#pragma unroll
    for (int j = 0; j < 16; ++j) { acc0[j] = b1[wq * 16 + j]; acc1[j] = acc0[j]; }
#pragma unroll 2
    for (int k = 0; k < D; ++k) {
        float t0 = xs[lane * LP + k];
        float t1 = xs[(lane + 64) * LP + k];
        const float4* wp = (const float4*)(W1 + k * D + wq * 16);
#pragma unroll
        for (int q = 0; q < 4; ++q) {
            float4 w = wp[q];
#pragma unroll
            for (int j = 0; j < 4; ++j) {
                float wv = ((const float*)&w)[j];
                acc0[q * 4 + j] = fmaf(t0, wv, acc0[q * 4 + j]);
                acc1[q * 4 + j] = fmaf(t1, wv, acc1[q * 4 + j]);
            }
        }
    }
    __syncthreads();
#pragma unroll
    for (int j = 0; j < 16; ++j) {
        xs[lane * LP + wq * 16 + j]        = fmaxf(acc0[j], 0.f);
        xs[(lane + 64) * LP + wq * 16 + j] = fmaxf(acc1[j], 0.f);
    }
    __syncthreads();

#pragma unroll
    for (int j = 0; j < 16; ++j) { acc0[j] = b2[wq * 16 + j]; acc1[j] = acc0[j]; }
#pragma unroll 2
    for (int k = 0; k < D; ++k) {
        float t0 = xs[lane * LP + k];
        float t1 = xs[(lane + 64) * LP + k];
        const float4* wp = (const float4*)(W2 + k * D + wq * 16);
#pragma unroll
        for (int q = 0; q < 4; ++q) {
            float4 w = wp[q];
#pragma unroll
            for (int j = 0; j < 4; ++j) {
                float wv = ((const float*)&w)[j];
                acc0[q * 4 + j] = fmaf(t0, wv, acc0[q * 4 + j]);
                acc1[q * 4 + j] = fmaf(t1, wv, acc1[q * 4 + j]);
            }
        }
    }

#pragma unroll
    for (int i = 0; i < 2; ++i) {
        int node = n0 + lane + 64 * i;
        if (node >= N_NODES) continue;
        float* a = i ? acc1 : acc0;
        if (WRITE_BF16) {
            u16* hp = outb + (size_t)node * D + wq * 16;
#pragma unroll
            for (int j = 0; j < 16; j += 2) {
                ushort2 pv;
                pv.x = f2bf(fmaxf(a[j], 0.f));
                pv.y = f2bf(fmaxf(a[j + 1], 0.f));
                *((ushort2*)(hp + j)) = pv;
            }
        } else {
            float* op = outf + (size_t)node * D + wq * 16;
#pragma unroll
            for (int q = 0; q < 4; ++q) {
                float4 w;
                w.x = a[q * 4]; w.y = a[q * 4 + 1];
                w.z = a[q * 4 + 2]; w.w = a[q * 4 + 3];
                ((float4*)op)[q] = w;
            }
        }
    }
}

extern "C" void kernel_launch(void* const* d_in, const int* in_sizes, int n_in,
                              void* d_out, int out_size, void* d_ws, size_t ws_size,
                              hipStream_t stream)
{
    const float* x  = (const float*)d_in[0];
    const int*   ei = (const int*)d_in[1];
    const float* W1 = (const float*)d_in[2];
    const float* b1 = (const float*)d_in[3];
    const float* W2 = (const float*)d_in[4];
    const float* b2 = (const float*)d_in[5];
    float* out = (float*)d_out;

    // workspace (~41.5 MB):
    //   qtail(512) | cnt(100096) | row_start(100096)
    //   queue (391*4800 u32 = 7.5MB) | sorted_src (7.5MB)
    //   xa_b (12.8MB bf16) | xb_b (12.8MB bf16; becomes hb after mlp1)
    int* qtail      = (int*)d_ws;
    int* cnt_arr    = qtail + 512;
    int* row_start  = cnt_arr + 100096;
    unsigned* queue = (unsigned*)(row_start + 100096);
    int* sorted_src = (int*)(queue + (size_t)NBUCKET * QCAP_B);
    u16* xa_b       = (u16*)(sorted_src + (size_t)NBUCKET * QCAP_B);
    u16* xb_b       = xa_b + (size_t)N_NODES * D;

    const int agg_blocks = (N_NODES + 3) / 4;       // 25000
    const int mlp_blocks = (N_NODES + 127) / 128;   // 782

    // ---- prep: qtail zero, x -> bf16, bucket sort, per-bucket CSR ----
    hipMemsetAsync(qtail, 0, 512 * sizeof(int), stream);
    convert_kernel<<<(N_NODES * D / 4) / 256, 256, 0, stream>>>(x, xb_b);
    sort_kernel<<<SORT_BLOCKS, 256, 0, stream>>>(ei, qtail, queue);
    bin3_kernel<<<NBUCKET, 256, 0, stream>>>(queue, qtail, cnt_arr, row_start, sorted_src);

    // ---- layer 1: hb = relu(MLP(xb + gather(xb))) ----
    aggregate_kernel<<<agg_blocks, 256, 0, stream>>>(xb_b, cnt_arr, row_start, sorted_src, xa_b);
    gin_mlp_kernel<1><<<mlp_blocks, 256, 0, stream>>>(xa_b, W1, b1, W2, b2, nullptr, xb_b);

    // ---- layer 2: out = MLP(hb + gather(hb)) ----
    aggregate_kernel<<<agg_blocks, 256, 0, stream>>>(xb_b, cnt_arr, row_start, sorted_src, xa_b);
    gin_mlp_kernel<0><<<mlp_blocks, 256, 0, stream>>>(xa_b, W1, b1, W2, b2, out, nullptr);
}

// Round 11
// 244.008 us; speedup vs baseline: 6.7201x; 1.1614x over previous
//
#include <hip/hip_runtime.h>

#define N_NODES 100000
#define N_EDGES 1600000
#define D 64
#define NBUCKET 391              // ceil(N_NODES/256), bucket = 256 dst nodes
#define QCAP_B 4800              // per-bucket queue cap (mean 4096, sd ~64)
#define EPB 4096                 // edges per sort block
#define SORT_BLOCKS 391          // ceil(N_EDGES/EPB)

typedef unsigned short u16;
typedef short bf16x8 __attribute__((ext_vector_type(8)));
typedef short s16x4  __attribute__((ext_vector_type(4)));
typedef float f32x4  __attribute__((ext_vector_type(4)));

__device__ __forceinline__ float bf2f(u16 u) {
    unsigned v = (unsigned)u << 16;
    float f;
    __builtin_memcpy(&f, &v, 4);
    return f;
}
__device__ __forceinline__ u16 f2bf(float f) {
    unsigned u;
    __builtin_memcpy(&u, &f, 4);
    u = (u + 0x7FFFu + ((u >> 16) & 1u)) >> 16;
    return (u16)u;
}

// ---------------------------------------------------------------------------
// x (f32) -> xb (bf16), 4 elems/thread.
// ---------------------------------------------------------------------------
__global__ __launch_bounds__(256) void convert_kernel(
    const float* __restrict__ x, u16* __restrict__ xb)
{
    int i = blockIdx.x * 256 + threadIdx.x;
    float4 v = ((const float4*)x)[i];
    ushort4 o;
    o.x = f2bf(v.x); o.y = f2bf(v.y); o.z = f2bf(v.z); o.w = f2bf(v.w);
    ((ushort4*)xb)[i] = o;
}

// ---------------------------------------------------------------------------
// Pack W1/W2 (fp32 64x64) into bf16 MFMA B-fragment order.
// frag f = (layer*4 + ct)*2 + kf holds B[k=kf*32+quad*8+j][n=ct*16+(lane&15)]
// at u16 offset f*512 + lane*8 + j  -> the MLP kernel loads one frag as a
// single coalesced dwordx4 per lane.
// ---------------------------------------------------------------------------
__global__ __launch_bounds__(256) void prep_weights_kernel(
    const float* __restrict__ W1, const float* __restrict__ W2,
    u16* __restrict__ Wf)
{
    int t = blockIdx.x * 256 + threadIdx.x;   // 16 frags * 64 lanes = 1024
    if (t >= 16 * 64) return;
    int f = t >> 6, lane = t & 63;
    int layer = f >> 3, ct = (f >> 1) & 3, kf = f & 1;
    const float* W = layer ? W2 : W1;
    int col = ct * 16 + (lane & 15);
    int krow = kf * 32 + (lane >> 4) * 8;
    u16* o = Wf + f * 512 + lane * 8;
#pragma unroll
    for (int j = 0; j < 8; ++j)
        o[j] = f2bf(W[(krow + j) * D + col]);
}

// ---------------------------------------------------------------------------
// Block-level counting sort of 4096 edges into 391 bucket queues (r9/r10).
// Entry packs (dst&255)<<17 | src.
// ---------------------------------------------------------------------------
__global__ __launch_bounds__(256) void sort_kernel(
    const int* __restrict__ ei, int* __restrict__ qtail,
    unsigned* __restrict__ queue)
{
    __shared__ int cnt[512];
    __shared__ int scan[512];
    __shared__ int gbase[512];
    __shared__ int run[512];
    __shared__ unsigned staged[EPB];
    __shared__ int gposa[EPB];

    int tid = threadIdx.x;
    int e0 = blockIdx.x * EPB;

    cnt[tid] = 0; cnt[tid + 256] = 0;
    run[tid] = 0; run[tid + 256] = 0;
    __syncthreads();

    for (int i = tid; i < EPB; i += 256) {
        int e = e0 + i;
        if (e < N_EDGES) {
            int dst = ei[N_EDGES + e];
            atomicAdd(&cnt[dst >> 8], 1);
        }
    }
    __syncthreads();
    scan[tid] = cnt[tid]; scan[tid + 256] = cnt[tid + 256];
    __syncthreads();
    for (int off = 1; off < 512; off <<= 1) {
        int v1 = (tid >= off) ? scan[tid - off] : 0;
        int v2 = scan[tid + 256 - off];
        __syncthreads();
        scan[tid] += v1;
        scan[tid + 256] += v2;
        __syncthreads();
    }
    if (tid < NBUCKET && cnt[tid] > 0)
        gbase[tid] = atomicAdd(&qtail[tid], cnt[tid]);
    int b2 = tid + 256;
    if (b2 < NBUCKET && cnt[b2] > 0)
        gbase[b2] = atomicAdd(&qtail[b2], cnt[b2]);
    __syncthreads();

    for (int i = tid; i < EPB; i += 256) {
        int e = e0 + i;
        if (e < N_EDGES) {
            int dst = ei[N_EDGES + e];
            int src = ei[e];
            int b = dst >> 8;
            int r = atomicAdd(&run[b], 1);
            int slot = scan[b] - cnt[b] + r;
            staged[slot] = ((unsigned)(dst & 255) << 17) | (unsigned)src;
            int gp = gbase[b] + r;
            gposa[slot] = (gp < QCAP_B) ? b * QCAP_B + gp : -1;
        }
    }
    __syncthreads();

    int total = scan[511];
    for (int i = tid; i < total; i += 256) {
        int gp = gposa[i];
        if (gp >= 0) queue[gp] = staged[i];
    }
}

// ---------------------------------------------------------------------------
// Per-bucket LDS counting sort -> exact CSR. Zero global atomics (r10).
// ---------------------------------------------------------------------------
__global__ __launch_bounds__(256) void bin3_kernel(
    const unsigned* __restrict__ queue, const int* __restrict__ qtail,
    int* __restrict__ cnt_out, int* __restrict__ row_start,
    int* __restrict__ sorted_src)
{
    __shared__ int cnt[256];
    __shared__ int scanv[256];
    __shared__ int run[256];
    __shared__ unsigned staged[QCAP_B];

    int tid = threadIdx.x;
    int b = blockIdx.x;
    cnt[tid] = 0; run[tid] = 0;
    __syncthreads();

    int n = min(qtail[b], QCAP_B);
    const unsigned* q = queue + (size_t)b * QCAP_B;

    for (int i = tid; i < n; i += 256) {
        unsigned e = q[i];
        staged[i] = e;
        atomicAdd(&cnt[e >> 17], 1);
    }
    __syncthreads();
    scanv[tid] = cnt[tid];
    __syncthreads();
    for (int off = 1; off < 256; off <<= 1) {
        int v = (tid >= off) ? scanv[tid - off] : 0;
        __syncthreads();
        scanv[tid] += v;
        __syncthreads();
    }

    int gb = b * QCAP_B;
    int node = b * 256 + tid;
    if (node < N_NODES) {
        cnt_out[node] = cnt[tid];
        row_start[node] = gb + scanv[tid] - cnt[tid];
    }

    for (int i = tid; i < n; i += 256) {
        unsigned e = staged[i];
        int r = (int)(e >> 17);
        int k = atomicAdd(&run[r], 1);
        int pos = gb + (scanv[r] - cnt[r]) + k;
        sorted_src[pos] = (int)(e & 0x1FFFFu);
    }
}

// ---------------------------------------------------------------------------
// Gather aggregation (unchanged from r10): wave per node, ILP-8 bf16 gathers.
// ---------------------------------------------------------------------------
__global__ __launch_bounds__(256) void aggregate_kernel(
    const u16* __restrict__ xb, const int* __restrict__ cnt_arr,
    const int* __restrict__ row_start, const int* __restrict__ sorted_src,
    u16* __restrict__ xa)
{
    int node = blockIdx.x * 4 + (threadIdx.x >> 6);
    int lane = threadIdx.x & 63;
    if (node >= N_NODES) return;

    int cnt = cnt_arr[node];
    int base = row_start[node];

    float a0 = bf2f(xb[(size_t)node * D + lane]);
    float a1 = 0.f, a2 = 0.f, a3 = 0.f;
    float a4 = 0.f, a5 = 0.f, a6 = 0.f, a7 = 0.f;

    for (int c = 0; c < cnt; c += 64) {
        int m = min(64, cnt - c);
        int s_vec = (lane < m) ? sorted_src[base + c + lane] : 0;
        int j = 0;
        for (; j + 8 <= m; j += 8) {
            int s0 = __shfl(s_vec, j);
            int s1 = __shfl(s_vec, j + 1);
            int s2 = __shfl(s_vec, j + 2);
            int s3 = __shfl(s_vec, j + 3);
            int s4 = __shfl(s_vec, j + 4);
            int s5 = __shfl(s_vec, j + 5);
            int s6 = __shfl(s_vec, j + 6);
            int s7 = __shfl(s_vec, j + 7);
            u16 v0 = xb[(size_t)s0 * D + lane];
            u16 v1 = xb[(size_t)s1 * D + lane];
            u16 v2 = xb[(size_t)s2 * D + lane];
            u16 v3 = xb[(size_t)s3 * D + lane];
            u16 v4 = xb[(size_t)s4 * D + lane];
            u16 v5 = xb[(size_t)s5 * D + lane];
            u16 v6 = xb[(size_t)s6 * D + lane];
            u16 v7 = xb[(size_t)s7 * D + lane];
            a0 += bf2f(v0); a1 += bf2f(v1); a2 += bf2f(v2); a3 += bf2f(v3);
            a4 += bf2f(v4); a5 += bf2f(v5); a6 += bf2f(v6); a7 += bf2f(v7);
        }
        for (; j + 4 <= m; j += 4) {
            int s0 = __shfl(s_vec, j);
            int s1 = __shfl(s_vec, j + 1);
            int s2 = __shfl(s_vec, j + 2);
            int s3 = __shfl(s_vec, j + 3);
            a0 += bf2f(xb[(size_t)s0 * D + lane]);
            a1 += bf2f(xb[(size_t)s1 * D + lane]);
            a2 += bf2f(xb[(size_t)s2 * D + lane]);
            a3 += bf2f(xb[(size_t)s3 * D + lane]);
        }
        for (; j < m; ++j) {
            int s = __shfl(s_vec, j);
            a0 += bf2f(xb[(size_t)s * D + lane]);
        }
    }
    float tot = ((a0 + a1) + (a2 + a3)) + ((a4 + a5) + (a6 + a7));
    xa[(size_t)node * D + lane] = f2bf(tot);
}

// ---------------------------------------------------------------------------
// MFMA MLP: out = [relu?]( relu(xa@W1+b1) @ W2 + b2 ), bf16 in, fp32 acc.
// Block = 256 = 4 waves; wave = 16 nodes x all 64 cols.
// A-frags (A[m=lane&15][k=quad*8+j], m120-verified) load DIRECTLY from
// global xa: one dwordx4 per K-half (wave covers a contiguous 2KB window).
// B-frags: prepacked Wf, one dwordx4 per frag. C/D layout (m89-verified):
// col=lane&15, row=quad*4+reg. Hidden u round-trips through WAVE-PRIVATE
// LDS rows (stride 136B -> layer-2 A-frag ds_read_b64 pairs, <=4-way
// aliased); no __syncthreads needed.
// ---------------------------------------------------------------------------
#define US 68   // u16 stride per node row (136 B)

template <int WRITE_BF16>
__global__ __launch_bounds__(256) void gin_mlp_kernel(
    const u16* __restrict__ xa, const u16* __restrict__ Wf,
    const float* __restrict__ b1, const float* __restrict__ b2,
    float* __restrict__ outf, u16* __restrict__ outb)
{
    __shared__ u16 us[64 * US];   // 8704 B

    int tid  = threadIdx.x;
    int lane = tid & 63;
    int w    = tid >> 6;
    int quad = lane >> 4;
    int l16  = lane & 15;
    int n0   = blockIdx.x * 64 + w * 16;

    // ---- layer 1: u = relu(xa @ W1 + b1) ----
    int arow = min(n0 + l16, N_NODES - 1);
    const u16* ab = xa + (size_t)arow * D + quad * 8;
    bf16x8 a0 = *(const bf16x8*)ab;          // k = quad*8+j
    bf16x8 a1 = *(const bf16x8*)(ab + 32);   // k = 32+quad*8+j

    f32x4 acc[4];
#pragma unroll
    for (int ct = 0; ct < 4; ++ct) {
        float bv = b1[ct * 16 + l16];
        acc[ct] = (f32x4){bv, bv, bv, bv};
        bf16x8 bf0 = *(const bf16x8*)(Wf + (size_t)((0 * 4 + ct) * 2 + 0) * 512 + lane * 8);
        bf16x8 bf1 = *(const bf16x8*)(Wf + (size_t)((0 * 4 + ct) * 2 + 1) * 512 + lane * 8);
        acc[ct] = __builtin_amdgcn_mfma_f32_16x16x32_bf16(a0, bf0, acc[ct], 0, 0, 0);
        acc[ct] = __builtin_amdgcn_mfma_f32_16x16x32_bf16(a1, bf1, acc[ct], 0, 0, 0);
    }

    // relu -> bf16 -> wave-private LDS rows (C-layout: row=quad*4+r, col)
#pragma unroll
    for (int ct = 0; ct < 4; ++ct)
#pragma unroll
        for (int r = 0; r < 4; ++r)
            us[(w * 16 + quad * 4 + r) * US + ct * 16 + l16] =
                f2bf(fmaxf(acc[ct][r], 0.f));

    // ---- layer 2: v = u @ W2 + b2 ----
    const u16* ub = &us[(w * 16 + l16) * US + quad * 8];
    s16x4 lo0 = *(const s16x4*)ub;
    s16x4 hi0 = *(const s16x4*)(ub + 4);
    s16x4 lo1 = *(const s16x4*)(ub + 32);
    s16x4 hi1 = *(const s16x4*)(ub + 36);
    bf16x8 u0 = __builtin_shufflevector(lo0, hi0, 0, 1, 2, 3, 4, 5, 6, 7);
    bf16x8 u1 = __builtin_shufflevector(lo1, hi1, 0, 1, 2, 3, 4, 5, 6, 7);

#pragma unroll
    for (int ct = 0; ct < 4; ++ct) {
        float bv = b2[ct * 16 + l16];
        acc[ct] = (f32x4){bv, bv, bv, bv};
        bf16x8 bf0 = *(const bf16x8*)(Wf + (size_t)((1 * 4 + ct) * 2 + 0) * 512 + lane * 8);
        bf16x8 bf1 = *(const bf16x8*)(Wf + (size_t)((1 * 4 + ct) * 2 + 1) * 512 + lane * 8);
        acc[ct] = __builtin_amdgcn_mfma_f32_16x16x32_bf16(u0, bf0, acc[ct], 0, 0, 0);
        acc[ct] = __builtin_amdgcn_mfma_f32_16x16x32_bf16(u1, bf1, acc[ct], 0, 0, 0);
    }

    // epilogue (C-layout scatter; 16-lane groups write contiguous runs)
#pragma unroll
    for (int r = 0; r < 4; ++r) {
        int node = n0 + quad * 4 + r;
        if (node >= N_NODES) continue;
#pragma unroll
        for (int ct = 0; ct < 4; ++ct) {
            if (WRITE_BF16)
                outb[(size_t)node * D + ct * 16 + l16] = f2bf(fmaxf(acc[ct][r], 0.f));
            else
                outf[(size_t)node * D + ct * 16 + l16] = acc[ct][r];
        }
    }
}

extern "C" void kernel_launch(void* const* d_in, const int* in_sizes, int n_in,
                              void* d_out, int out_size, void* d_ws, size_t ws_size,
                              hipStream_t stream)
{
    const float* x  = (const float*)d_in[0];
    const int*   ei = (const int*)d_in[1];
    const float* W1 = (const float*)d_in[2];
    const float* b1 = (const float*)d_in[3];
    const float* W2 = (const float*)d_in[4];
    const float* b2 = (const float*)d_in[5];
    float* out = (float*)d_out;

    // workspace (~41.5 MB):
    //   qtail(512) | cnt(100096) | row_start(100096)
    //   queue (391*4800 u32) | sorted_src (391*4800 int)
    //   Wf (8192 u16) | xa_b (12.8MB bf16) | xb_b (12.8MB bf16 -> hb)
    int* qtail      = (int*)d_ws;
    int* cnt_arr    = qtail + 512;
    int* row_start  = cnt_arr + 100096;
    unsigned* queue = (unsigned*)(row_start + 100096);
    int* sorted_src = (int*)(queue + (size_t)NBUCKET * QCAP_B);
    u16* Wf         = (u16*)(sorted_src + (size_t)NBUCKET * QCAP_B);
    u16* xa_b       = Wf + 8192;
    u16* xb_b       = xa_b + (size_t)N_NODES * D;

    const int agg_blocks = (N_NODES + 3) / 4;       // 25000
    const int mlp_blocks = (N_NODES + 63) / 64;     // 1563

    // ---- prep: qtail zero, x -> bf16, weight pack, sort, per-bucket CSR ----
    hipMemsetAsync(qtail, 0, 512 * sizeof(int), stream);
    convert_kernel<<<(N_NODES * D / 4) / 256, 256, 0, stream>>>(x, xb_b);
    prep_weights_kernel<<<4, 256, 0, stream>>>(W1, W2, Wf);
    sort_kernel<<<SORT_BLOCKS, 256, 0, stream>>>(ei, qtail, queue);
    bin3_kernel<<<NBUCKET, 256, 0, stream>>>(queue, qtail, cnt_arr, row_start, sorted_src);

    // ---- layer 1: hb = relu(MLP(xb + gather(xb))) ----
    aggregate_kernel<<<agg_blocks, 256, 0, stream>>>(xb_b, cnt_arr, row_start, sorted_src, xa_b);
    gin_mlp_kernel<1><<<mlp_blocks, 256, 0, stream>>>(xa_b, Wf, b1, b2, nullptr, xb_b);

    // ---- layer 2: out = MLP(hb + gather(hb)) ----
    aggregate_kernel<<<agg_blocks, 256, 0, stream>>>(xb_b, cnt_arr, row_start, sorted_src, xa_b);
    gin_mlp_kernel<0><<<mlp_blocks, 256, 0, stream>>>(xa_b, Wf, b1, b2, out, nullptr);
}